// Round 1
// baseline (316.353 us; speedup 1.0000x reference)
//
#include <hip/hip_runtime.h>
#include <cmath>

namespace {

typedef float vf4 __attribute__((ext_vector_type(4)));

constexpr int kH    = 160;
constexpr int kW    = 160;
constexpr int kC    = 256;
constexpr int kN    = 1024;
constexpr int kCrop = 14;
constexpr int kPO   = 7;                     // pooled output is 7x7
constexpr int kOutPos = kN * kPO * kPO;      // 50176 pooled positions
constexpr int kBlocks = kOutPos / 4;         // 12544 (divisible by 8)
constexpr int kWC  = kW * kC;                // elements per image row
constexpr int kHWC = kH * kW * kC;           // elements per image

// One wave (64 lanes) per pooled output position; lane handles 4 channels
// (float4). 256-thread block = 4 waves = 4 pooled outputs.
//
// All geometry (ROI index, cell coords, row/col offsets) is wave-uniform:
// force it into SGPRs via readfirstlane so the 16 gather loads become
// {SGPR base + SALU offset + one shared lane*16 VGPR} instead of 16
// 64-bit VGPR pointer pairs. This cuts ~45 VGPRs of address state ->
// higher occupancy (latency hiding for the ~600-900 cy gather) and far
// fewer VALU instructions per wave.
//
// XCD swizzle: remap blockIdx so each XCD receives a CONTIGUOUS run of
// logical blocks -> all ~13 blocks of one ROI share an XCD -> the ROI's
// column-reuse hits the 4 MB per-XCD L2 instead of falling to L3.
__global__ __launch_bounds__(256, 4) void roi_pool_kernel(
    const float* __restrict__ img,     // [B,H,W,C] NHWC
    const float* __restrict__ rois,    // [N,5]  (img_id, x0, y0, x1, y1)
    const float* __restrict__ iminfo,  // [N,2]  (H_img, W_img)
    float* __restrict__ out)           // [N,7,7,C]
{
    const int wave = threadIdx.x >> 6;
    const int lane = threadIdx.x & 63;

    // physical -> logical block remap (XCD-contiguous)
    const int xcd = blockIdx.x & 7;
    const int lb  = xcd * (kBlocks >> 3) + (blockIdx.x >> 3);

    // pooled position: wave-uniform -> SGPR (divisions become SALU magic-mul)
    const int p  = __builtin_amdgcn_readfirstlane(lb * 4 + wave);
    const int n  = p / (kPO * kPO);
    const int r  = p - n * (kPO * kPO);
    const int ph = r / kPO;
    const int pw = r - ph * kPO;

    // Per-ROI scalars: uniform address -> s_load
    const float bidf = rois[n * 5 + 0];
    const float bx0  = rois[n * 5 + 1];
    const float by0  = rois[n * 5 + 2];
    const float bx1  = rois[n * 5 + 3];
    const float by1  = rois[n * 5 + 4];
    const float him  = iminfo[n * 2 + 0];
    const float wim  = iminfo[n * 2 + 1];
    const int b = __builtin_amdgcn_readfirstlane((int)bidf);

    const float y1 = by0 / him;
    const float x1 = bx0 / wim;
    const float y2 = by1 / him;
    const float x2 = bx1 / wim;

    const float ybase = y1 * (float)(kH - 1);
    const float xbase = x1 * (float)(kW - 1);
    const float ystep = ((y2 - y1) * (float)(kH - 1)) / (float)(kCrop - 1);
    const float xstep = ((x2 - x1) * (float)(kW - 1)) / (float)(kCrop - 1);

    float ylerp[2], xlerp[2];
    float vy[2], vx[2];
    int rlo[2], rhi[2];   // row element offsets (uniform, SGPR)
    int clo[2], chi[2];   // col element offsets (uniform, SGPR)
#pragma unroll
    for (int s = 0; s < 2; ++s) {
        const float y = ybase + (float)(2 * ph + s) * ystep;
        vy[s] = ((y >= 0.0f) && (y <= (float)(kH - 1))) ? 1.0f : 0.0f;
        const float yf = floorf(y);
        ylerp[s] = y - yf;
        const int yl = (int)fminf(fmaxf(yf, 0.0f), (float)(kH - 1));
        const int yh = (int)fminf(fmaxf(yf + 1.0f, 0.0f), (float)(kH - 1));
        rlo[s] = __builtin_amdgcn_readfirstlane(yl) * kWC;
        rhi[s] = __builtin_amdgcn_readfirstlane(yh) * kWC;

        const float x = xbase + (float)(2 * pw + s) * xstep;
        vx[s] = ((x >= 0.0f) && (x <= (float)(kW - 1))) ? 1.0f : 0.0f;
        const float xf = floorf(x);
        xlerp[s] = x - xf;
        const int xl = (int)fminf(fmaxf(xf, 0.0f), (float)(kW - 1));
        const int xh = (int)fminf(fmaxf(xf + 1.0f, 0.0f), (float)(kW - 1));
        clo[s] = __builtin_amdgcn_readfirstlane(xl) * kC;
        chi[s] = __builtin_amdgcn_readfirstlane(xh) * kC;
    }

    const int cl = lane * 4;                         // channel offset (VGPR)
    const float* __restrict__ base = img + (size_t)b * (size_t)kHWC;

    // ---- issue all 16 corner loads before any math (max MLP) ----
    // Each address = SGPR base + (SALU uniform offset + lane*4) elements.
    vf4 d[16];
#pragma unroll
    for (int sy = 0; sy < 2; ++sy) {
#pragma unroll
        for (int sx = 0; sx < 2; ++sx) {
            const int k = (sy * 2 + sx) * 4;
            d[k + 0] = *(const vf4*)(base + (rlo[sy] + clo[sx] + cl));
            d[k + 1] = *(const vf4*)(base + (rlo[sy] + chi[sx] + cl));
            d[k + 2] = *(const vf4*)(base + (rhi[sy] + clo[sx] + cl));
            d[k + 3] = *(const vf4*)(base + (rhi[sy] + chi[sx] + cl));
        }
    }

    // acc MUST start at -INF: an all-valid window of negatives must yield the
    // negative max (invalid samples contribute literal 0 via the mask, which
    // then participates in the max — matching reference where+reduce_window).
    vf4 acc = { -INFINITY, -INFINITY, -INFINITY, -INFINITY };
#pragma unroll
    for (int sy = 0; sy < 2; ++sy) {
#pragma unroll
        for (int sx = 0; sx < 2; ++sx) {
            const int k = (sy * 2 + sx) * 4;
            const vf4 tl = d[k + 0];
            const vf4 tr = d[k + 1];
            const vf4 bl = d[k + 2];
            const vf4 br = d[k + 3];
            const float xw = xlerp[sx];
            const float yw = ylerp[sy];
            const float m  = vy[sy] * vx[sx];   // 0 or 1
            const float t0 = tl.x + (tr.x - tl.x) * xw;
            const float t1 = tl.y + (tr.y - tl.y) * xw;
            const float t2 = tl.z + (tr.z - tl.z) * xw;
            const float t3 = tl.w + (tr.w - tl.w) * xw;
            const float b0 = bl.x + (br.x - bl.x) * xw;
            const float b1 = bl.y + (br.y - bl.y) * xw;
            const float b2 = bl.z + (br.z - bl.z) * xw;
            const float b3 = bl.w + (br.w - bl.w) * xw;
            acc.x = fmaxf(acc.x, (t0 + (b0 - t0) * yw) * m);
            acc.y = fmaxf(acc.y, (t1 + (b1 - t1) * yw) * m);
            acc.z = fmaxf(acc.z, (t2 + (b2 - t2) * yw) * m);
            acc.w = fmaxf(acc.w, (t3 + (b3 - t3) * yw) * m);
        }
    }

    // One vectorized nontemporal store (global_store_dwordx4 nt): the 51 MB
    // output stream must not evict the gather working set from L2/L3.
    vf4* op = (vf4*)(out + (size_t)p * kC + cl);
    __builtin_nontemporal_store(acc, op);
}

} // namespace

extern "C" void kernel_launch(void* const* d_in, const int* in_sizes, int n_in,
                              void* d_out, int out_size, void* d_ws, size_t ws_size,
                              hipStream_t stream) {
    const float* img    = (const float*)d_in[0];   // (8,160,160,256) f32
    const float* rois   = (const float*)d_in[1];   // (1024,5) f32
    const float* iminfo = (const float*)d_in[2];   // (1024,2) f32
    float* out = (float*)d_out;                    // (1024,7,7,256) f32

    dim3 grid(kBlocks);   // 12544 blocks, 4 pooled outputs each
    dim3 block(256);
    roi_pool_kernel<<<grid, block, 0, stream>>>(img, rois, iminfo, out);
}